// Round 1
// baseline (136.136 us; speedup 1.0000x reference)
//
#include <hip/hip_runtime.h>
#include <hip/hip_bf16.h>

#define TOKENS 64
#define IN_F 8192
#define OUT_F 8192
#define CB 256

typedef _Float16 half8 __attribute__((ext_vector_type(8)));
typedef float f32x4 __attribute__((ext_vector_type(4)));

// ---------------------------------------------------------------------------
// Kernel 1: xh = FWHT(x * SU) * (1/sqrt(IN_F) * Wscale[0])  -> fp16, stored in
// MFMA-A-FRAGMENT ORDER (k2 A-load = 64 lanes x 16B contiguous):
//   xh_frag[((ks*4 + mt)*64 + quad*16 + l15)*8 + j]
//     = xh_row[mt*16 + l15][ks*32 + quad*8 + j]
// R9: float4 global loads via bit-remapped element ownership:
//   e(r,t) = ((r>>2)<<10) | (t<<2) | (r&3)
// (FWHT is separable per bit in any order: regs own bits {0,1,10,11,12},
//  lanes bits 2..7, waves bits 8..9 — butterfly code unchanged.)
// ---------------------------------------------------------------------------
__global__ __launch_bounds__(256) void k_fwht_in(const float* __restrict__ x,
                                                 const float* __restrict__ SU,
                                                 const float* __restrict__ Wscale,
                                                 _Float16* __restrict__ xh_frag)
{
    __shared__ float buf[256 * 33];
    __shared__ _Float16 xrowP[256 * 40];
    const int t    = threadIdx.x;
    const int lane = t & 63;
    const int w    = t >> 6;
    const int row  = blockIdx.x;

    float v[32];
    const float* xr = x + row * IN_F;
#pragma unroll
    for (int rh = 0; rh < 8; ++rh) {
        int base = (rh << 10) | (t << 2);
        float4 xv = *(const float4*)(xr + base);
        float4 sv = *(const float4*)(SU + base);
        v[rh * 4 + 0] = xv.x * sv.x;
        v[rh * 4 + 1] = xv.y * sv.y;
        v[rh * 4 + 2] = xv.z * sv.z;
        v[rh * 4 + 3] = xv.w * sv.w;
    }
    // FWHT group A: register-index bits (e-bits {0,1,10,11,12})
#pragma unroll
    for (int h = 1; h < 32; h <<= 1) {
#pragma unroll
        for (int r = 0; r < 32; ++r) {
            if ((r & h) == 0) {
                float a = v[r], b = v[r + h];
                v[r] = a + b;
                v[r + h] = a - b;
            }
        }
    }
    // FWHT group B: lane bits (e-bits 2..7) via shfl_xor
#pragma unroll
    for (int m = 1; m < 64; m <<= 1) {
        bool upper = (lane & m) != 0;
#pragma unroll
        for (int r = 0; r < 32; ++r) {
            float p = __shfl_xor(v[r], m, 64);
            v[r] = upper ? (p - v[r]) : (v[r] + p);
        }
    }
    // FWHT group C: wave bits (e-bits 8..9) via LDS H4
#pragma unroll
    for (int r = 0; r < 32; ++r) buf[t * 33 + r] = v[r];
    __syncthreads();
    {
        float s1 = (w & 1) ? -1.f : 1.f;
        float s2 = (w & 2) ? -1.f : 1.f;
        float s3 = s1 * s2;
#pragma unroll
        for (int r = 0; r < 32; ++r) {
            float a0 = buf[(0 * 64 + lane) * 33 + r];
            float a1 = buf[(1 * 64 + lane) * 33 + r];
            float a2 = buf[(2 * 64 + lane) * 33 + r];
            float a3 = buf[(3 * 64 + lane) * 33 + r];
            v[r] = a0 + s1 * a1 + s2 * a2 + s3 * a3;
        }
    }
    const float scale = 0.011048543456039806f * Wscale[0];  // 1/sqrt(8192)*Wscale
#pragma unroll
    for (int r = 0; r < 32; ++r) {
        int c = ((r >> 2) << 10) | (t << 2) | (r & 3);      // e(r,t)
        int idx = (c & 31) + (c >> 5) * 40;
        xrowP[idx] = (_Float16)(v[r] * scale);
    }
    __syncthreads();
    {
        const int mt  = row >> 4;
        const int l15 = row & 15;
        _Float16* base = xh_frag + ((size_t)(t * 4 + mt) * 64 + l15) * 8;
#pragma unroll
        for (int g = 0; g < 4; ++g) {
            half8 val = *(const half8*)&xrowP[t * 40 + g * 8];
            *(half8*)(base + g * 16 * 8) = val;
        }
    }
}

// ---------------------------------------------------------------------------
// Kernel 2: fused dequant GEMM. R9: Phase-A serial staging DISSOLVED into the
// K-loop. Wave w only gathers cols w*64 + s*4 + quad -> per-wave private LDS
// slice sqw[64 rows][68 ints] (int4-aligned, 2-way gather conflicts as before).
// Per K-step: 1 int4 global load/lane (lane = row, that step's 4 cols), staged
// 2 iterations ahead via a 4-slot register ring, 1 ds_write_b128; step s+3 is
// written immediately before its QGATHER (same-wave DS ops are in-order).
// No pre-loop Qidxs barrier: the 32MB Qidxs HBM stream overlaps MFMA+gather.
// red (4*64*68 f32 = 69632B) exactly aliases the staging region; epilogue
// barrier unchanged. Loops fully unrolled so ring[] indices are static.
// ---------------------------------------------------------------------------
#define SQW 68
__global__ __launch_bounds__(256, 2) void k_qgemm(const _Float16* __restrict__ xh_frag,
                                                  const int* __restrict__ Qidxs,
                                                  const float* __restrict__ grid,
                                                  float* __restrict__ y_part)
{
    __shared__ __align__(16) _Float16 glds[CB * 8];       // 4 KB fp16 codebook
    // union region: K-loop -> int sq[4 waves][64 rows][68]  (69632 B);
    //               epilogue -> float red[4*64*68]          (69632 B)
    __shared__ __align__(16) char uni[4 * 64 * SQW * 4];
    int*   sq  = (int*)uni;
    float* red = (float*)uni;

    const int tid = threadIdx.x;
    const int g   = blockIdx.x >> 2; // n-group (128)
    const int p   = blockIdx.x & 3;  // K-part (4)
    const int n0  = g * 64;

    const int lane = tid & 63;
    const int w    = tid >> 6;        // wave id -> K sub-chunk
    const int col  = lane & 15;
    const int quad = lane >> 4;

    int* sqw = sq + w * (64 * SQW);
    const int* qsrc = Qidxs + (size_t)(n0 + lane) * 1024 + p * 256 + w * 64;

    // issue ring loads for steps 0..3 before the codebook barrier
    int4 ring[4];
    ring[0] = *(const int4*)(qsrc + 0);
    ring[1] = *(const int4*)(qsrc + 4);
    ring[2] = *(const int4*)(qsrc + 8);
    ring[3] = *(const int4*)(qsrc + 12);

    // stage codebook -> LDS fp16
    {
        const float4* gp = (const float4*)grid + tid * 2;
        float4 g0 = gp[0];
        float4 g1 = gp[1];
        _Float16* gl = &glds[tid * 8];
        gl[0] = (_Float16)g0.x; gl[1] = (_Float16)g0.y;
        gl[2] = (_Float16)g0.z; gl[3] = (_Float16)g0.w;
        gl[4] = (_Float16)g1.x; gl[5] = (_Float16)g1.y;
        gl[6] = (_Float16)g1.z; gl[7] = (_Float16)g1.w;
    }
    __syncthreads();   // glds visibility only

    // write steps 0..2 into own slice; refill slot 0 with step 4
    {
        int4* dst = (int4*)&sqw[lane * SQW];
        dst[0] = ring[0];
        dst[1] = ring[1];
        dst[2] = ring[2];
    }
    ring[0] = *(const int4*)(qsrc + 16);   // step 4 -> slot 0

    // gather: q(s)[nt] = sqw[(nt*16+col)*SQW + s*4 + quad]
#define QGATHER(dst4, s_)                                             \
    {                                                                 \
        int cc = (s_) * 4 + quad;                                     \
        dst4.x = sqw[(0 * 16 + col) * SQW + cc];                      \
        dst4.y = sqw[(1 * 16 + col) * SQW + cc];                      \
        dst4.z = sqw[(2 * 16 + col) * SQW + cc];                      \
        dst4.w = sqw[(3 * 16 + col) * SQW + cc];                      \
    }

    // A fragment base: global kstep Ks = p*64 + w*16 + s; frag (s,mt) at +(s*4+mt)*512
    const _Float16* abase = xh_frag + ((size_t)(p * 64 + w * 16) * 4 * 64 + lane) * 8;

    f32x4 acc[4][4] = {};   // [nt][mt]

    // ---- pipeline prologue: b_c = b(0), qv1 = q(1), qv2 = q(2) ----
    int4 qv1, qv2;
    half8 b_c[4];
    {
        int4 qv0;
        QGATHER(qv0, 0);
        QGATHER(qv1, 1);
        QGATHER(qv2, 2);
        b_c[0] = *(const half8*)&glds[qv0.x * 8];
        b_c[1] = *(const half8*)&glds[qv0.y * 8];
        b_c[2] = *(const half8*)&glds[qv0.z * 8];
        b_c[3] = *(const half8*)&glds[qv0.w * 8];
    }
    half8 a_c[4], a_n[4];
#pragma unroll
    for (int mt = 0; mt < 4; ++mt) {
        a_c[mt] = *(const half8*)(abase + (size_t)(0 * 4 + mt) * 512);
        a_n[mt] = *(const half8*)(abase + (size_t)(1 * 4 + mt) * 512);
    }

    // ---- main K-loop, s = 0..11: stage step s+3, load step s+5 ----
#pragma unroll
    for (int s = 0; s < 12; ++s) {
        const int s3 = s + 3;                          // <= 14
        const int s2 = s + 2;                          // <= 13
        const int s5 = (s + 5 < 16) ? s + 5 : 15;      // clamped redundant load
        *(int4*)&sqw[lane * SQW + s3 * 4] = ring[s3 & 3];   // stage step s+3
        ring[(s + 1) & 3] = *(const int4*)(qsrc + s5 * 4);  // load step s+5
        int4 qn;
        QGATHER(qn, s3);                               // q(s+3) — just written
        half8 b_n[4], a_nn[4];
        b_n[0] = *(const half8*)&glds[qv1.x * 8];      // b(s+1)
        b_n[1] = *(const half8*)&glds[qv1.y * 8];
        b_n[2] = *(const half8*)&glds[qv1.z * 8];
        b_n[3] = *(const half8*)&glds[qv1.w * 8];
#pragma unroll
        for (int mt = 0; mt < 4; ++mt)
            a_nn[mt] = *(const half8*)(abase + (size_t)(s2 * 4 + mt) * 512); // a(s+2)
#pragma unroll
        for (int nt = 0; nt < 4; ++nt)
#pragma unroll
            for (int mt = 0; mt < 4; ++mt)
                acc[nt][mt] = __builtin_amdgcn_mfma_f32_16x16x32_f16(
                    a_c[mt], b_c[nt], acc[nt][mt], 0, 0, 0);
#pragma unroll
        for (int nt = 0; nt < 4; ++nt) b_c[nt] = b_n[nt];
        qv1 = qv2; qv2 = qn;
#pragma unroll
        for (int mt = 0; mt < 4; ++mt) { a_c[mt] = a_n[mt]; a_n[mt] = a_nn[mt]; }
    }

    // ---- tail, s = 12..15: no more loads; step 15 written once at s=12 ----
#pragma unroll
    for (int s = 12; s < 16; ++s) {
        const int s3 = 15;
        const int s2 = (s + 2 < 16) ? s + 2 : 15;
        if (s == 12)
            *(int4*)&sqw[lane * SQW + 15 * 4] = ring[3];    // stage step 15
        int4 qn;
        QGATHER(qn, s3);
        half8 b_n[4], a_nn[4];
        b_n[0] = *(const half8*)&glds[qv1.x * 8];
        b_n[1] = *(const half8*)&glds[qv1.y * 8];
        b_n[2] = *(const half8*)&glds[qv1.z * 8];
        b_n[3] = *(const half8*)&glds[qv1.w * 8];
#pragma unroll
        for (int mt = 0; mt < 4; ++mt)
            a_nn[mt] = *(const half8*)(abase + (size_t)(s2 * 4 + mt) * 512);
#pragma unroll
        for (int nt = 0; nt < 4; ++nt)
#pragma unroll
            for (int mt = 0; mt < 4; ++mt)
                acc[nt][mt] = __builtin_amdgcn_mfma_f32_16x16x32_f16(
                    a_c[mt], b_c[nt], acc[nt][mt], 0, 0, 0);
#pragma unroll
        for (int nt = 0; nt < 4; ++nt) b_c[nt] = b_n[nt];
        qv1 = qv2; qv2 = qn;
#pragma unroll
        for (int mt = 0; mt < 4; ++mt) { a_c[mt] = a_n[mt]; a_n[mt] = a_nn[mt]; }
    }

    // ---- epilogue: red aliases sq; barrier ensures all waves left the K-loop
    __syncthreads();
    // C/D layout: token r = mt*16 + quad*4 + i, feature c = nt*16 + col
#pragma unroll
    for (int nt = 0; nt < 4; ++nt)
#pragma unroll
        for (int mt = 0; mt < 4; ++mt)
#pragma unroll
            for (int i = 0; i < 4; ++i) {
                int r = mt * 16 + quad * 4 + i;
                int c = nt * 16 + col;
                red[(w * 64 + r) * 68 + c] = acc[nt][mt][i];
            }
    __syncthreads();
    float* yp = y_part + (size_t)p * TOKENS * OUT_F;
#pragma unroll
    for (int j = 0; j < 16; ++j) {
        int idx = j * 256 + tid;
        int rr = idx >> 6, cc = idx & 63;
        float s = (red[(0 * 64 + rr) * 68 + cc] + red[(1 * 64 + rr) * 68 + cc])
                + (red[(2 * 64 + rr) * 68 + cc] + red[(3 * 64 + rr) * 68 + cc]);
        yp[(size_t)rr * OUT_F + n0 + cc] = s;
    }
#undef QGATHER
}

// ---------------------------------------------------------------------------
// Kernel 3: fold 4 K-part partials, FWHT, * 1/sqrt(OUT_F) * SV + bias
// R9: float4 loads/stores via the same e(r,t) bit remap as k1.
// ---------------------------------------------------------------------------
__global__ __launch_bounds__(256) void k_fwht_out(const float* __restrict__ y_part,
                                                  const float* __restrict__ SV,
                                                  const float* __restrict__ bias,
                                                  float* __restrict__ out)
{
    __shared__ float buf[256 * 33];
    const int t    = threadIdx.x;
    const int lane = t & 63;
    const int w    = t >> 6;
    const int row  = blockIdx.x;

    const float* y0 = y_part + (size_t)row * OUT_F;
    const size_t ps = (size_t)TOKENS * OUT_F;

    float v[32];
#pragma unroll
    for (int rh = 0; rh < 8; ++rh) {
        int base = (rh << 10) | (t << 2);
        float4 a = *(const float4*)(y0 + base);
        float4 b = *(const float4*)(y0 + ps + base);
        float4 c = *(const float4*)(y0 + 2 * ps + base);
        float4 d = *(const float4*)(y0 + 3 * ps + base);
        v[rh * 4 + 0] = (a.x + b.x) + (c.x + d.x);
        v[rh * 4 + 1] = (a.y + b.y) + (c.y + d.y);
        v[rh * 4 + 2] = (a.z + b.z) + (c.z + d.z);
        v[rh * 4 + 3] = (a.w + b.w) + (c.w + d.w);
    }
#pragma unroll
    for (int h = 1; h < 32; h <<= 1) {
#pragma unroll
        for (int r = 0; r < 32; ++r) {
            if ((r & h) == 0) {
                float a = v[r], b = v[r + h];
                v[r] = a + b;
                v[r + h] = a - b;
            }
        }
    }
#pragma unroll
    for (int m = 1; m < 64; m <<= 1) {
        bool upper = (lane & m) != 0;
#pragma unroll
        for (int r = 0; r < 32; ++r) {
            float p = __shfl_xor(v[r], m, 64);
            v[r] = upper ? (p - v[r]) : (v[r] + p);
        }
    }
#pragma unroll
    for (int r = 0; r < 32; ++r) buf[t * 33 + r] = v[r];
    __syncthreads();
    {
        float s1 = (w & 1) ? -1.f : 1.f;
        float s2 = (w & 2) ? -1.f : 1.f;
        float s3 = s1 * s2;
#pragma unroll
        for (int r = 0; r < 32; ++r) {
            float a0 = buf[(0 * 64 + lane) * 33 + r];
            float a1 = buf[(1 * 64 + lane) * 33 + r];
            float a2 = buf[(2 * 64 + lane) * 33 + r];
            float a3 = buf[(3 * 64 + lane) * 33 + r];
            v[r] = a0 + s1 * a1 + s2 * a2 + s3 * a3;
        }
    }
    const float scale = 0.011048543456039806f;  // 1/sqrt(8192)
    float* oo = out + (size_t)row * OUT_F;
#pragma unroll
    for (int rh = 0; rh < 8; ++rh) {
        int base = (rh << 10) | (t << 2);
        float4 sv = *(const float4*)(SV + base);
        float4 bv = *(const float4*)(bias + base);
        float4 o;
        o.x = v[rh * 4 + 0] * scale * sv.x + bv.x;
        o.y = v[rh * 4 + 1] * scale * sv.y + bv.y;
        o.z = v[rh * 4 + 2] * scale * sv.z + bv.z;
        o.w = v[rh * 4 + 3] * scale * sv.w + bv.w;
        *(float4*)(oo + base) = o;
    }
}

extern "C" void kernel_launch(void* const* d_in, const int* in_sizes, int n_in,
                              void* d_out, int out_size, void* d_ws, size_t ws_size,
                              hipStream_t stream) {
    const float* x      = (const float*)d_in[0];
    const float* SU     = (const float*)d_in[1];
    const float* SV     = (const float*)d_in[2];
    const float* grid   = (const float*)d_in[3];
    const float* Wscale = (const float*)d_in[4];
    const float* bias   = (const float*)d_in[5];
    const int*   Qidxs  = (const int*)d_in[6];
    float* out = (float*)d_out;

    // ws layout: xh_frag 1 MB | y_part 8 MB
    _Float16* xh_frag = (_Float16*)d_ws;
    float*    y_part  = (float*)((char*)d_ws + ((size_t)1 << 20));

    k_fwht_in<<<TOKENS, 256, 0, stream>>>(x, SU, Wscale, xh_frag);
    k_qgemm<<<512, 256, 0, stream>>>(xh_frag, Qidxs, grid, y_part);
    k_fwht_out<<<TOKENS, 256, 0, stream>>>(y_part, SV, bias, out);
}

// Round 2
// 112.589 us; speedup vs baseline: 1.2091x; 1.2091x over previous
//
#include <hip/hip_runtime.h>
#include <hip/hip_bf16.h>

#define TOKENS 64
#define IN_F 8192
#define OUT_F 8192
#define CB 256

typedef _Float16 half8 __attribute__((ext_vector_type(8)));
typedef float f32x4 __attribute__((ext_vector_type(4)));

// ---------------------------------------------------------------------------
// Kernel 1: xh = FWHT(x * SU) * (1/sqrt(IN_F) * Wscale[0])  -> fp16, stored in
// MFMA-A-FRAGMENT ORDER (k2 A-load = 64 lanes x 16B contiguous):
//   xh_frag[((ks*4 + mt)*64 + quad*16 + l15)*8 + j]
//     = xh_row[mt*16 + l15][ks*32 + quad*8 + j]
// R10 (kept from R9): float4 global loads via bit-remapped element ownership:
//   e(r,t) = ((r>>2)<<10) | (t<<2) | (r&3)
// (FWHT is separable per bit in any order: regs own bits {0,1,10,11,12},
//  lanes bits 2..7, waves bits 8..9 — butterfly code unchanged.)
// ---------------------------------------------------------------------------
__global__ __launch_bounds__(256) void k_fwht_in(const float* __restrict__ x,
                                                 const float* __restrict__ SU,
                                                 const float* __restrict__ Wscale,
                                                 _Float16* __restrict__ xh_frag)
{
    __shared__ float buf[256 * 33];
    __shared__ _Float16 xrowP[256 * 40];
    const int t    = threadIdx.x;
    const int lane = t & 63;
    const int w    = t >> 6;
    const int row  = blockIdx.x;

    float v[32];
    const float* xr = x + row * IN_F;
#pragma unroll
    for (int rh = 0; rh < 8; ++rh) {
        int base = (rh << 10) | (t << 2);
        float4 xv = *(const float4*)(xr + base);
        float4 sv = *(const float4*)(SU + base);
        v[rh * 4 + 0] = xv.x * sv.x;
        v[rh * 4 + 1] = xv.y * sv.y;
        v[rh * 4 + 2] = xv.z * sv.z;
        v[rh * 4 + 3] = xv.w * sv.w;
    }
    // FWHT group A: register-index bits (e-bits {0,1,10,11,12})
#pragma unroll
    for (int h = 1; h < 32; h <<= 1) {
#pragma unroll
        for (int r = 0; r < 32; ++r) {
            if ((r & h) == 0) {
                float a = v[r], b = v[r + h];
                v[r] = a + b;
                v[r + h] = a - b;
            }
        }
    }
    // FWHT group B: lane bits (e-bits 2..7) via shfl_xor
#pragma unroll
    for (int m = 1; m < 64; m <<= 1) {
        bool upper = (lane & m) != 0;
#pragma unroll
        for (int r = 0; r < 32; ++r) {
            float p = __shfl_xor(v[r], m, 64);
            v[r] = upper ? (p - v[r]) : (v[r] + p);
        }
    }
    // FWHT group C: wave bits (e-bits 8..9) via LDS H4
#pragma unroll
    for (int r = 0; r < 32; ++r) buf[t * 33 + r] = v[r];
    __syncthreads();
    {
        float s1 = (w & 1) ? -1.f : 1.f;
        float s2 = (w & 2) ? -1.f : 1.f;
        float s3 = s1 * s2;
#pragma unroll
        for (int r = 0; r < 32; ++r) {
            float a0 = buf[(0 * 64 + lane) * 33 + r];
            float a1 = buf[(1 * 64 + lane) * 33 + r];
            float a2 = buf[(2 * 64 + lane) * 33 + r];
            float a3 = buf[(3 * 64 + lane) * 33 + r];
            v[r] = a0 + s1 * a1 + s2 * a2 + s3 * a3;
        }
    }
    const float scale = 0.011048543456039806f * Wscale[0];  // 1/sqrt(8192)*Wscale
#pragma unroll
    for (int r = 0; r < 32; ++r) {
        int c = ((r >> 2) << 10) | (t << 2) | (r & 3);      // e(r,t)
        int idx = (c & 31) + (c >> 5) * 40;
        xrowP[idx] = (_Float16)(v[r] * scale);
    }
    __syncthreads();
    {
        const int mt  = row >> 4;
        const int l15 = row & 15;
        _Float16* base = xh_frag + ((size_t)(t * 4 + mt) * 64 + l15) * 8;
#pragma unroll
        for (int g = 0; g < 4; ++g) {
            half8 val = *(const half8*)&xrowP[t * 40 + g * 8];
            *(half8*)(base + g * 16 * 8) = val;
        }
    }
}

// ---------------------------------------------------------------------------
// Kernel 2: fused dequant GEMM with in-kernel Qidxs staging. R10 = exact R8
// revert (best measured point, 113.0 µs wall).
// R9 POST-MORTEM (staging dissolved into K-loop): REGRESSED ~18 µs of kernel
// time — per-step per-lane int4 loads from 4KB-strided rows are 64 distinct
// cachelines per VMEM (worst-case address divergence). Qidxs staging cannot
// be both coalesced and K-chunked (K is the fast axis of each row); the
// upfront coalesced Phase A is structurally right.
//
// Grid: 512 blocks = 128 n-groups x 4 K-parts; 4 waves split the K-part.
// Wave tile M=64 x N=64, 16x16x32 f16 MFMA, acc 64 VGPR.
// Phase A: stage 64-row x 256-int Qidxs slice into LDS (wave-coalesced 1KB
//   row reads; stride 261 -> conflict-free gathers, 5*col distinct mod 32).
// Phase B: 16-step K-loop; q = 4x ds_read_b32, B = LDS codebook 16B gather,
//   A = contiguous 1KB global fragment loads. No barriers in the K-loop.
// Epilogue: red ALIASES sq's LDS -> 73.7 KB total, 2 blocks/CU.
// ---------------------------------------------------------------------------
#define SQ_STRIDE 261
__global__ __launch_bounds__(256, 2) void k_qgemm(const _Float16* __restrict__ xh_frag,
                                                  const int* __restrict__ Qidxs,
                                                  const float* __restrict__ grid,
                                                  float* __restrict__ y_part)
{
    __shared__ __align__(16) _Float16 glds[CB * 8];       // 4 KB fp16 codebook
    // union region: phase A/B -> int sq[64*261] (66.8 KB);
    //               epilogue  -> float red[4*64*68] (69.6 KB)
    __shared__ __align__(16) char uni[4 * 64 * 68 * 4];   // 69632 B
    int*   sq  = (int*)uni;
    float* red = (float*)uni;

    const int tid = threadIdx.x;
    const int g   = blockIdx.x >> 2; // n-group (128)
    const int p   = blockIdx.x & 3;  // K-part (4)
    const int n0  = g * 64;

    // stage codebook -> LDS fp16
    {
        const float4* gp = (const float4*)grid + tid * 2;
        float4 g0 = gp[0];
        float4 g1 = gp[1];
        _Float16* gl = &glds[tid * 8];
        gl[0] = (_Float16)g0.x; gl[1] = (_Float16)g0.y;
        gl[2] = (_Float16)g0.z; gl[3] = (_Float16)g0.w;
        gl[4] = (_Float16)g1.x; gl[5] = (_Float16)g1.y;
        gl[6] = (_Float16)g1.z; gl[7] = (_Float16)g1.w;
    }
    // Phase A: stage Qidxs slice (rows n0..n0+63, int cols p*256..p*256+255)
#pragma unroll
    for (int i = 0; i < 16; ++i) {
        int idx4 = i * 256 + tid;
        int r  = idx4 >> 6;
        int c4 = idx4 & 63;
        int4 vv = *(const int4*)(Qidxs + (size_t)(n0 + r) * 1024 + p * 256 + c4 * 4);
        int* dst = &sq[r * SQ_STRIDE + c4 * 4];
        dst[0] = vv.x; dst[1] = vv.y; dst[2] = vv.z; dst[3] = vv.w;
    }
    __syncthreads();

    const int lane = tid & 63;
    const int w    = tid >> 6;        // wave id -> K sub-chunk
    const int col  = lane & 15;
    const int quad = lane >> 4;

    // index gather from sq: q(s)[nt] = sq[(nt*16+col)*261 + w*64 + s*4 + quad]
    const int cbase = w * 64 + quad;
#define QGATHER(dst4, s)                                              \
    {                                                                 \
        int cc = cbase + (s) * 4;                                     \
        dst4.x = sq[(0 * 16 + col) * SQ_STRIDE + cc];                 \
        dst4.y = sq[(1 * 16 + col) * SQ_STRIDE + cc];                 \
        dst4.z = sq[(2 * 16 + col) * SQ_STRIDE + cc];                 \
        dst4.w = sq[(3 * 16 + col) * SQ_STRIDE + cc];                 \
    }

    // A fragment base: global kstep Ks = p*64 + w*16 + s; frag (s,mt) at +(s*4+mt)*512
    const _Float16* abase = xh_frag + ((size_t)(p * 64 + w * 16) * 4 * 64 + lane) * 8;

    f32x4 acc[4][4] = {};   // [nt][mt]

    // ---- pipeline prologue: b_c = b(0), qv1 = q(1), qv2 = q(2) ----
    int4 qv1, qv2;
    half8 b_c[4];
    {
        int4 qv0;
        QGATHER(qv0, 0);
        QGATHER(qv1, 1);
        QGATHER(qv2, 2);
        b_c[0] = *(const half8*)&glds[qv0.x * 8];
        b_c[1] = *(const half8*)&glds[qv0.y * 8];
        b_c[2] = *(const half8*)&glds[qv0.z * 8];
        b_c[3] = *(const half8*)&glds[qv0.w * 8];
    }
    half8 a_c[4], a_n[4];
#pragma unroll
    for (int mt = 0; mt < 4; ++mt) {
        a_c[mt] = *(const half8*)(abase + (size_t)(0 * 4 + mt) * 512);
        a_n[mt] = *(const half8*)(abase + (size_t)(1 * 4 + mt) * 512);
    }

#pragma unroll 4
    for (int s = 0; s < 16; ++s) {
        const int s3 = (s + 3 < 16 ? s + 3 : 15);
        const int s2 = (s + 2 < 16 ? s + 2 : 15);
        int4 qn;
        QGATHER(qn, s3);                                 // q(s+3), LDS
        half8 b_n[4], a_nn[4];
        b_n[0] = *(const half8*)&glds[qv1.x * 8];        // b(s+1)
        b_n[1] = *(const half8*)&glds[qv1.y * 8];
        b_n[2] = *(const half8*)&glds[qv1.z * 8];
        b_n[3] = *(const half8*)&glds[qv1.w * 8];
#pragma unroll
        for (int mt = 0; mt < 4; ++mt)
            a_nn[mt] = *(const half8*)(abase + (size_t)(s2 * 4 + mt) * 512); // a(s+2)
#pragma unroll
        for (int nt = 0; nt < 4; ++nt)
#pragma unroll
            for (int mt = 0; mt < 4; ++mt)
                acc[nt][mt] = __builtin_amdgcn_mfma_f32_16x16x32_f16(
                    a_c[mt], b_c[nt], acc[nt][mt], 0, 0, 0);
#pragma unroll
        for (int nt = 0; nt < 4; ++nt) b_c[nt] = b_n[nt];
        qv1 = qv2; qv2 = qn;
#pragma unroll
        for (int mt = 0; mt < 4; ++mt) { a_c[mt] = a_n[mt]; a_n[mt] = a_nn[mt]; }
    }

    // ---- epilogue: red aliases sq; barrier ensures all waves left the K-loop
    __syncthreads();
    // C/D layout: token r = mt*16 + quad*4 + i, feature c = nt*16 + col
#pragma unroll
    for (int nt = 0; nt < 4; ++nt)
#pragma unroll
        for (int mt = 0; mt < 4; ++mt)
#pragma unroll
            for (int i = 0; i < 4; ++i) {
                int r = mt * 16 + quad * 4 + i;
                int c = nt * 16 + col;
                red[(w * 64 + r) * 68 + c] = acc[nt][mt][i];
            }
    __syncthreads();
    float* yp = y_part + (size_t)p * TOKENS * OUT_F;
#pragma unroll
    for (int j = 0; j < 16; ++j) {
        int idx = j * 256 + tid;
        int rr = idx >> 6, cc = idx & 63;
        float s = (red[(0 * 64 + rr) * 68 + cc] + red[(1 * 64 + rr) * 68 + cc])
                + (red[(2 * 64 + rr) * 68 + cc] + red[(3 * 64 + rr) * 68 + cc]);
        yp[(size_t)rr * OUT_F + n0 + cc] = s;
    }
#undef QGATHER
}

// ---------------------------------------------------------------------------
// Kernel 3: fold 4 K-part partials, FWHT, * 1/sqrt(OUT_F) * SV + bias
// R10 (kept from R9): float4 loads/stores via the same e(r,t) bit remap as k1.
// ---------------------------------------------------------------------------
__global__ __launch_bounds__(256) void k_fwht_out(const float* __restrict__ y_part,
                                                  const float* __restrict__ SV,
                                                  const float* __restrict__ bias,
                                                  float* __restrict__ out)
{
    __shared__ float buf[256 * 33];
    const int t    = threadIdx.x;
    const int lane = t & 63;
    const int w    = t >> 6;
    const int row  = blockIdx.x;

    const float* y0 = y_part + (size_t)row * OUT_F;
    const size_t ps = (size_t)TOKENS * OUT_F;

    float v[32];
#pragma unroll
    for (int rh = 0; rh < 8; ++rh) {
        int base = (rh << 10) | (t << 2);
        float4 a = *(const float4*)(y0 + base);
        float4 b = *(const float4*)(y0 + ps + base);
        float4 c = *(const float4*)(y0 + 2 * ps + base);
        float4 d = *(const float4*)(y0 + 3 * ps + base);
        v[rh * 4 + 0] = (a.x + b.x) + (c.x + d.x);
        v[rh * 4 + 1] = (a.y + b.y) + (c.y + d.y);
        v[rh * 4 + 2] = (a.z + b.z) + (c.z + d.z);
        v[rh * 4 + 3] = (a.w + b.w) + (c.w + d.w);
    }
#pragma unroll
    for (int h = 1; h < 32; h <<= 1) {
#pragma unroll
        for (int r = 0; r < 32; ++r) {
            if ((r & h) == 0) {
                float a = v[r], b = v[r + h];
                v[r] = a + b;
                v[r + h] = a - b;
            }
        }
    }
#pragma unroll
    for (int m = 1; m < 64; m <<= 1) {
        bool upper = (lane & m) != 0;
#pragma unroll
        for (int r = 0; r < 32; ++r) {
            float p = __shfl_xor(v[r], m, 64);
            v[r] = upper ? (p - v[r]) : (v[r] + p);
        }
    }
#pragma unroll
    for (int r = 0; r < 32; ++r) buf[t * 33 + r] = v[r];
    __syncthreads();
    {
        float s1 = (w & 1) ? -1.f : 1.f;
        float s2 = (w & 2) ? -1.f : 1.f;
        float s3 = s1 * s2;
#pragma unroll
        for (int r = 0; r < 32; ++r) {
            float a0 = buf[(0 * 64 + lane) * 33 + r];
            float a1 = buf[(1 * 64 + lane) * 33 + r];
            float a2 = buf[(2 * 64 + lane) * 33 + r];
            float a3 = buf[(3 * 64 + lane) * 33 + r];
            v[r] = a0 + s1 * a1 + s2 * a2 + s3 * a3;
        }
    }
    const float scale = 0.011048543456039806f;  // 1/sqrt(8192)
    float* oo = out + (size_t)row * OUT_F;
#pragma unroll
    for (int rh = 0; rh < 8; ++rh) {
        int base = (rh << 10) | (t << 2);
        float4 sv = *(const float4*)(SV + base);
        float4 bv = *(const float4*)(bias + base);
        float4 o;
        o.x = v[rh * 4 + 0] * scale * sv.x + bv.x;
        o.y = v[rh * 4 + 1] * scale * sv.y + bv.y;
        o.z = v[rh * 4 + 2] * scale * sv.z + bv.z;
        o.w = v[rh * 4 + 3] * scale * sv.w + bv.w;
        *(float4*)(oo + base) = o;
    }
}

extern "C" void kernel_launch(void* const* d_in, const int* in_sizes, int n_in,
                              void* d_out, int out_size, void* d_ws, size_t ws_size,
                              hipStream_t stream) {
    const float* x      = (const float*)d_in[0];
    const float* SU     = (const float*)d_in[1];
    const float* SV     = (const float*)d_in[2];
    const float* grid   = (const float*)d_in[3];
    const float* Wscale = (const float*)d_in[4];
    const float* bias   = (const float*)d_in[5];
    const int*   Qidxs  = (const int*)d_in[6];
    float* out = (float*)d_out;

    // ws layout: xh_frag 1 MB | y_part 8 MB
    _Float16* xh_frag = (_Float16*)d_ws;
    float*    y_part  = (float*)((char*)d_ws + ((size_t)1 << 20));

    k_fwht_in<<<TOKENS, 256, 0, stream>>>(x, SU, Wscale, xh_frag);
    k_qgemm<<<512, 256, 0, stream>>>(xh_frag, Qidxs, grid, y_part);
    k_fwht_out<<<TOKENS, 256, 0, stream>>>(y_part, SV, bias, out);
}

// Round 3
// 110.787 us; speedup vs baseline: 1.2288x; 1.0163x over previous
//
#include <hip/hip_runtime.h>
#include <hip/hip_bf16.h>

#define TOKENS 64
#define IN_F 8192
#define OUT_F 8192
#define CB 256

typedef _Float16 half8 __attribute__((ext_vector_type(8)));
typedef float f32x4 __attribute__((ext_vector_type(4)));

// ---------------------------------------------------------------------------
// Kernel 1: xh = FWHT(x * SU) * (1/sqrt(IN_F) * Wscale[0])  -> fp16, stored in
// MFMA-A-FRAGMENT ORDER (k2 A-load = 64 lanes x 16B contiguous):
//   xh_frag[((ks*4 + mt)*64 + quad*16 + l15)*8 + j]
//     = xh_row[mt*16 + l15][ks*32 + quad*8 + j]
// float4 global loads via bit-remapped element ownership:
//   e(r,t) = ((r>>2)<<10) | (t<<2) | (r&3)
// ---------------------------------------------------------------------------
__global__ __launch_bounds__(256) void k_fwht_in(const float* __restrict__ x,
                                                 const float* __restrict__ SU,
                                                 const float* __restrict__ Wscale,
                                                 _Float16* __restrict__ xh_frag)
{
    __shared__ float buf[256 * 33];
    __shared__ _Float16 xrowP[256 * 40];
    const int t    = threadIdx.x;
    const int lane = t & 63;
    const int w    = t >> 6;
    const int row  = blockIdx.x;

    float v[32];
    const float* xr = x + row * IN_F;
#pragma unroll
    for (int rh = 0; rh < 8; ++rh) {
        int base = (rh << 10) | (t << 2);
        float4 xv = *(const float4*)(xr + base);
        float4 sv = *(const float4*)(SU + base);
        v[rh * 4 + 0] = xv.x * sv.x;
        v[rh * 4 + 1] = xv.y * sv.y;
        v[rh * 4 + 2] = xv.z * sv.z;
        v[rh * 4 + 3] = xv.w * sv.w;
    }
#pragma unroll
    for (int h = 1; h < 32; h <<= 1) {
#pragma unroll
        for (int r = 0; r < 32; ++r) {
            if ((r & h) == 0) {
                float a = v[r], b = v[r + h];
                v[r] = a + b;
                v[r + h] = a - b;
            }
        }
    }
#pragma unroll
    for (int m = 1; m < 64; m <<= 1) {
        bool upper = (lane & m) != 0;
#pragma unroll
        for (int r = 0; r < 32; ++r) {
            float p = __shfl_xor(v[r], m, 64);
            v[r] = upper ? (p - v[r]) : (v[r] + p);
        }
    }
#pragma unroll
    for (int r = 0; r < 32; ++r) buf[t * 33 + r] = v[r];
    __syncthreads();
    {
        float s1 = (w & 1) ? -1.f : 1.f;
        float s2 = (w & 2) ? -1.f : 1.f;
        float s3 = s1 * s2;
#pragma unroll
        for (int r = 0; r < 32; ++r) {
            float a0 = buf[(0 * 64 + lane) * 33 + r];
            float a1 = buf[(1 * 64 + lane) * 33 + r];
            float a2 = buf[(2 * 64 + lane) * 33 + r];
            float a3 = buf[(3 * 64 + lane) * 33 + r];
            v[r] = a0 + s1 * a1 + s2 * a2 + s3 * a3;
        }
    }
    const float scale = 0.011048543456039806f * Wscale[0];  // 1/sqrt(8192)*Wscale
#pragma unroll
    for (int r = 0; r < 32; ++r) {
        int c = ((r >> 2) << 10) | (t << 2) | (r & 3);      // e(r,t)
        int idx = (c & 31) + (c >> 5) * 40;
        xrowP[idx] = (_Float16)(v[r] * scale);
    }
    __syncthreads();
    {
        const int mt  = row >> 4;
        const int l15 = row & 15;
        _Float16* base = xh_frag + ((size_t)(t * 4 + mt) * 64 + l15) * 8;
#pragma unroll
        for (int g = 0; g < 4; ++g) {
            half8 val = *(const half8*)&xrowP[t * 40 + g * 8];
            *(half8*)(base + g * 16 * 8) = val;
        }
    }
}

// ---------------------------------------------------------------------------
// Kernel 2 (R11): BARRIER-FREE fused dequant GEMM.
// Key insight: wave w's gathers only touch int-cols w*64..w*64+63 — so each
// wave stages ITS OWN column slice (64 rows x 64 ints, 4x256B cache-aligned
// segments per int4 load — NOT R9's 64-line scatter) into a WAVE-PRIVATE LDS
// slice, u8-packed (values < 256): word sq[w][r][s] bytes = quads of step s.
//  - no __syncthreads before the epilogue (same-wave DS ordering covers RAW);
//    waves desynchronize -> staging VMEM of one wave hides under gathers/MFMA
//    of the other 7 resident waves.
//  - q-gather: 1 ds_read_b32 per nt, 16 distinct banks, 4-lane same-address
//    broadcast -> conflict-free (was 4x ds_read_b32).
//  - codebook staged per-wave redundantly (identical bytes, benign race).
//  - epilogue: red chunked per-nt (4*64*17 f32 = exactly the 17408B staging
//    region, aliased; each wave overwrites only its own dead slice).
// LDS: 4KB glds + 17KB uni = 21.4KB.
// ---------------------------------------------------------------------------
#define SQWW 17   // u32 words per staged row (16 + 1 pad)
__global__ __launch_bounds__(256, 2) void k_qgemm(const _Float16* __restrict__ xh_frag,
                                                  const int* __restrict__ Qidxs,
                                                  const float* __restrict__ grid,
                                                  float* __restrict__ y_part)
{
    __shared__ __align__(16) _Float16 glds[CB * 8];            // 4 KB fp16 codebook
    __shared__ __align__(16) unsigned int uni[4 * 64 * SQWW];  // 17408 B
    float* red = (float*)uni;

    const int tid  = threadIdx.x;
    const int lane = tid & 63;
    const int w    = tid >> 6;        // wave id -> K sub-chunk
    const int col  = lane & 15;
    const int quad = lane >> 4;
    const int g    = blockIdx.x >> 2; // n-group (128)
    const int p    = blockIdx.x & 3;  // K-part (4)
    const int n0   = g * 64;

    unsigned int* sqw = uni + w * (64 * SQWW);   // wave-private slice

    // ---- wave-private Qidxs staging: rows 0..63, int-cols w*64..w*64+63 ----
    // lane (col,quad), iter i: row = i*4+quad, cols col*4..col*4+3 (int4).
    // pack 4 idx -> u32; word sq[w][row][col] bytes 0..3 = quads 0..3 of step col.
    {
        const int* qbase = Qidxs + (size_t)n0 * 1024 + p * 256 + w * 64 + col * 4;
#pragma unroll
        for (int i = 0; i < 16; ++i) {
            int r = i * 4 + quad;
            int4 vv = *(const int4*)(qbase + (size_t)r * 1024);
            unsigned int pk = (unsigned int)(vv.x & 255) |
                              ((unsigned int)(vv.y & 255) << 8) |
                              ((unsigned int)(vv.z & 255) << 16) |
                              ((unsigned int)(vv.w & 255) << 24);
            sqw[r * SQWW + col] = pk;
        }
    }
    // ---- codebook -> LDS fp16, per-wave redundant (benign same-value race) ----
    {
#pragma unroll
        for (int e = 0; e < 4; ++e) {
            int entry = lane + 64 * e;                 // 8-cyc-optimal bank walk
            float4 g0 = *((const float4*)grid + entry * 2);
            float4 g1 = *((const float4*)grid + entry * 2 + 1);
            half8 hv;
            hv[0] = (_Float16)g0.x; hv[1] = (_Float16)g0.y;
            hv[2] = (_Float16)g0.z; hv[3] = (_Float16)g0.w;
            hv[4] = (_Float16)g1.x; hv[5] = (_Float16)g1.y;
            hv[6] = (_Float16)g1.z; hv[7] = (_Float16)g1.w;
            *(half8*)&glds[entry * 8] = hv;
        }
    }
    __asm__ volatile("s_waitcnt lgkmcnt(0)" ::: "memory");
    __builtin_amdgcn_sched_barrier(0);

    const int shq = quad * 8;

    // q-word read: step s, nt: sq[w][(nt*16+col)][s]; 4-lane broadcast, no conflicts
#define QWREAD(dst, s_)                                              \
    {                                                                \
        dst[0] = sqw[(0 * 16 + col) * SQWW + (s_)];                  \
        dst[1] = sqw[(1 * 16 + col) * SQWW + (s_)];                  \
        dst[2] = sqw[(2 * 16 + col) * SQWW + (s_)];                  \
        dst[3] = sqw[(3 * 16 + col) * SQWW + (s_)];                  \
    }

    // A fragment base: global kstep Ks = p*64 + w*16 + s; frag (s,mt) at +(s*4+mt)*512
    const _Float16* abase = xh_frag + ((size_t)(p * 64 + w * 16) * 4 * 64 + lane) * 8;

    f32x4 acc[4][4] = {};   // [nt][mt]

    // ---- pipeline prologue ----
    unsigned int qw_c[4], qw_n[4];
    QWREAD(qw_c, 0);
    QWREAD(qw_n, 1);
    half8 b_c[4];
#pragma unroll
    for (int nt = 0; nt < 4; ++nt) {
        unsigned int q = (qw_c[nt] >> shq) & 255u;
        b_c[nt] = *(const half8*)&glds[q * 8];
    }
    half8 a_c[4], a_n[4];
#pragma unroll
    for (int mt = 0; mt < 4; ++mt) {
        a_c[mt] = *(const half8*)(abase + (size_t)(0 * 4 + mt) * 512);
        a_n[mt] = *(const half8*)(abase + (size_t)(1 * 4 + mt) * 512);
    }

#pragma unroll 4
    for (int s = 0; s < 16; ++s) {
        const int s2q = (s + 2 < 16 ? s + 2 : 15);
        unsigned int qw_nn[4];
        QWREAD(qw_nn, s2q);                              // q-words(s+2)
        half8 b_n[4], a_nn[4];
#pragma unroll
        for (int nt = 0; nt < 4; ++nt) {
            unsigned int q = (qw_n[nt] >> shq) & 255u;   // b(s+1)
            b_n[nt] = *(const half8*)&glds[q * 8];
        }
#pragma unroll
        for (int mt = 0; mt < 4; ++mt)
            a_nn[mt] = *(const half8*)(abase + (size_t)(s2q * 4 + mt) * 512); // a(s+2)
#pragma unroll
        for (int nt = 0; nt < 4; ++nt)
#pragma unroll
            for (int mt = 0; mt < 4; ++mt)
                acc[nt][mt] = __builtin_amdgcn_mfma_f32_16x16x32_f16(
                    a_c[mt], b_c[nt], acc[nt][mt], 0, 0, 0);
#pragma unroll
        for (int nt = 0; nt < 4; ++nt) { b_c[nt] = b_n[nt]; qw_n[nt] = qw_nn[nt]; }
#pragma unroll
        for (int mt = 0; mt < 4; ++mt) { a_c[mt] = a_n[mt]; a_n[mt] = a_nn[mt]; }
    }

    // ---- epilogue: per-nt chunked cross-wave reduce; red aliases staging ----
    // wave w writes only red[w] (= its own dead sq slice); barrier per chunk.
    float* redw = red + w * (64 * SQWW);
    float* yp = y_part + (size_t)p * TOKENS * OUT_F;
#pragma unroll
    for (int nt = 0; nt < 4; ++nt) {
#pragma unroll
        for (int mt = 0; mt < 4; ++mt)
#pragma unroll
            for (int i = 0; i < 4; ++i) {
                int r = mt * 16 + quad * 4 + i;
                redw[r * SQWW + col] = acc[nt][mt][i];
            }
        __syncthreads();
#pragma unroll
        for (int j = 0; j < 4; ++j) {
            int idx = j * 256 + tid;     // 0..1023
            int rr = idx >> 4;           // token row 0..63
            int cc = idx & 15;           // col within chunk
            float s = (red[(0 * 64 + rr) * SQWW + cc] + red[(1 * 64 + rr) * SQWW + cc])
                    + (red[(2 * 64 + rr) * SQWW + cc] + red[(3 * 64 + rr) * SQWW + cc]);
            yp[(size_t)rr * OUT_F + n0 + nt * 16 + cc] = s;
        }
        __syncthreads();
    }
#undef QWREAD
}

// ---------------------------------------------------------------------------
// Kernel 3: fold 4 K-part partials, FWHT, * 1/sqrt(OUT_F) * SV + bias
// float4 loads/stores via the same e(r,t) bit remap as k1.
// ---------------------------------------------------------------------------
__global__ __launch_bounds__(256) void k_fwht_out(const float* __restrict__ y_part,
                                                  const float* __restrict__ SV,
                                                  const float* __restrict__ bias,
                                                  float* __restrict__ out)
{
    __shared__ float buf[256 * 33];
    const int t    = threadIdx.x;
    const int lane = t & 63;
    const int w    = t >> 6;
    const int row  = blockIdx.x;

    const float* y0 = y_part + (size_t)row * OUT_F;
    const size_t ps = (size_t)TOKENS * OUT_F;

    float v[32];
#pragma unroll
    for (int rh = 0; rh < 8; ++rh) {
        int base = (rh << 10) | (t << 2);
        float4 a = *(const float4*)(y0 + base);
        float4 b = *(const float4*)(y0 + ps + base);
        float4 c = *(const float4*)(y0 + 2 * ps + base);
        float4 d = *(const float4*)(y0 + 3 * ps + base);
        v[rh * 4 + 0] = (a.x + b.x) + (c.x + d.x);
        v[rh * 4 + 1] = (a.y + b.y) + (c.y + d.y);
        v[rh * 4 + 2] = (a.z + b.z) + (c.z + d.z);
        v[rh * 4 + 3] = (a.w + b.w) + (c.w + d.w);
    }
#pragma unroll
    for (int h = 1; h < 32; h <<= 1) {
#pragma unroll
        for (int r = 0; r < 32; ++r) {
            if ((r & h) == 0) {
                float a = v[r], b = v[r + h];
                v[r] = a + b;
                v[r + h] = a - b;
            }
        }
    }
#pragma unroll
    for (int m = 1; m < 64; m <<= 1) {
        bool upper = (lane & m) != 0;
#pragma unroll
        for (int r = 0; r < 32; ++r) {
            float p = __shfl_xor(v[r], m, 64);
            v[r] = upper ? (p - v[r]) : (v[r] + p);
        }
    }
#pragma unroll
    for (int r = 0; r < 32; ++r) buf[t * 33 + r] = v[r];
    __syncthreads();
    {
        float s1 = (w & 1) ? -1.f : 1.f;
        float s2 = (w & 2) ? -1.f : 1.f;
        float s3 = s1 * s2;
#pragma unroll
        for (int r = 0; r < 32; ++r) {
            float a0 = buf[(0 * 64 + lane) * 33 + r];
            float a1 = buf[(1 * 64 + lane) * 33 + r];
            float a2 = buf[(2 * 64 + lane) * 33 + r];
            float a3 = buf[(3 * 64 + lane) * 33 + r];
            v[r] = a0 + s1 * a1 + s2 * a2 + s3 * a3;
        }
    }
    const float scale = 0.011048543456039806f;  // 1/sqrt(8192)
    float* oo = out + (size_t)row * OUT_F;
#pragma unroll
    for (int rh = 0; rh < 8; ++rh) {
        int base = (rh << 10) | (t << 2);
        float4 sv = *(const float4*)(SV + base);
        float4 bv = *(const float4*)(bias + base);
        float4 o;
        o.x = v[rh * 4 + 0] * scale * sv.x + bv.x;
        o.y = v[rh * 4 + 1] * scale * sv.y + bv.y;
        o.z = v[rh * 4 + 2] * scale * sv.z + bv.z;
        o.w = v[rh * 4 + 3] * scale * sv.w + bv.w;
        *(float4*)(oo + base) = o;
    }
}

extern "C" void kernel_launch(void* const* d_in, const int* in_sizes, int n_in,
                              void* d_out, int out_size, void* d_ws, size_t ws_size,
                              hipStream_t stream) {
    const float* x      = (const float*)d_in[0];
    const float* SU     = (const float*)d_in[1];
    const float* SV     = (const float*)d_in[2];
    const float* grid   = (const float*)d_in[3];
    const float* Wscale = (const float*)d_in[4];
    const float* bias   = (const float*)d_in[5];
    const int*   Qidxs  = (const int*)d_in[6];
    float* out = (float*)d_out;

    // ws layout: xh_frag 1 MB | y_part 8 MB
    _Float16* xh_frag = (_Float16*)d_ws;
    float*    y_part  = (float*)((char*)d_ws + ((size_t)1 << 20));

    k_fwht_in<<<TOKENS, 256, 0, stream>>>(x, SU, Wscale, xh_frag);
    k_qgemm<<<512, 256, 0, stream>>>(xh_frag, Qidxs, grid, y_part);
    k_fwht_out<<<TOKENS, 256, 0, stream>>>(y_part, SV, bias, out);
}